// Round 5
// baseline (324.656 us; speedup 1.0000x reference)
//
#include <hip/hip_runtime.h>
#include <math.h>

// Round 5: OUTPUT IS FP32 (R3~R4 agreement + pair-packing arithmetic proved
// the 2.34 error was bf16 stores read back as fp32). R3's MFMA pipeline,
// unconditional fp32->bf16 convert prepass, fp32 final store. Semantics
// validated by R3/R4 cross-agreement (two independent implementations).

typedef __bf16 bf16;
typedef __bf16 bf16x8 __attribute__((ext_vector_type(8)));
typedef float  f32x4  __attribute__((ext_vector_type(4)));

#define MFMA_BF16(a, b, c) __builtin_amdgcn_mfma_f32_16x16x32_bf16((a), (b), (c), 0, 0, 0)

#define SEQ  4096
#define NH   12
#define HD   64
#define DM   768          // NH*HD
#define NQKV 2304         // 3*DM
#define ATTN_SCALE 0.12f
#define RMS_EPS 1.1920928955078125e-07f
#define NEG_INF -3.0e38f

// ---------------------------------------------------------------------------
// fp32 -> bf16 convert. n multiple of 2048; 8 elements/thread.
// ---------------------------------------------------------------------------
__global__ __launch_bounds__(256) void convert_in(const float* __restrict__ src,
                                                  bf16* __restrict__ dst, int n)
{
  const int i0 = (blockIdx.x * 256 + threadIdx.x) * 8;
  if (i0 >= n) return;
  f32x4 a = *(const f32x4*)(src + i0);
  f32x4 b = *(const f32x4*)(src + i0 + 4);
  bf16x8 o;
#pragma unroll
  for (int j = 0; j < 4; j++) { o[j] = (bf16)a[j]; o[j + 4] = (bf16)b[j]; }
  *(bf16x8*)(dst + i0) = o;
}

// ---------------------------------------------------------------------------
// QKV GEMM: C[m][n] = sum_k x[m][k]*qkv_w[n][k]; 64x64 tile, BK=32, 4 waves.
// Epilogue scatters: Q,K as [h][t][d]; V directly transposed as [h][d][t].
// ---------------------------------------------------------------------------
__global__ __launch_bounds__(256) void gemm_qkv(
    const bf16* __restrict__ A,      // x: [SEQ][DM]
    const bf16* __restrict__ B,      // qkv_w: [NQKV][DM]
    bf16* __restrict__ Qb, bf16* __restrict__ Kb, bf16* __restrict__ Vt)
{
  __shared__ bf16 As[64][40];
  __shared__ bf16 Bs[64][40];
  const int m0 = blockIdx.x * 64, n0 = blockIdx.y * 64;
  const int tid = threadIdx.x;
  const int lane = tid & 63, w = tid >> 6;
  const int c16 = lane & 15, q4 = lane >> 4;
  const int sr = tid >> 2, sc = tid & 3;          // 64 rows x 32 k = 2048 = 256*8
  const f32x4 vzero = {0.f, 0.f, 0.f, 0.f};
  f32x4 acc[4] = {vzero, vzero, vzero, vzero};

  for (int k0 = 0; k0 < DM; k0 += 32) {
    *(bf16x8*)&As[sr][sc * 8] = *(const bf16x8*)&A[(m0 + sr) * DM + k0 + sc * 8];
    *(bf16x8*)&Bs[sr][sc * 8] = *(const bf16x8*)&B[(n0 + sr) * DM + k0 + sc * 8];
    __syncthreads();
    bf16x8 af = *(const bf16x8*)&As[w * 16 + c16][q4 * 8];
#pragma unroll
    for (int nt = 0; nt < 4; nt++) {
      bf16x8 bfr = *(const bf16x8*)&Bs[nt * 16 + c16][q4 * 8];
      acc[nt] = MFMA_BF16(af, bfr, acc[nt]);
    }
    __syncthreads();
  }
#pragma unroll
  for (int nt = 0; nt < 4; nt++) {
    const int n = n0 + nt * 16 + c16;
    const int kidx = n / DM;
    const int rr = n - kidx * DM;
    const int h = rr >> 6, d = rr & 63;
    const int mb = m0 + w * 16 + q4 * 4;
    if (kidx == 2) {
#pragma unroll
      for (int rg = 0; rg < 4; rg++)
        Vt[((h * HD) + d) * SEQ + mb + rg] = (bf16)acc[nt][rg];
    } else {
      bf16* dst = kidx ? Kb : Qb;
#pragma unroll
      for (int rg = 0; rg < 4; rg++)
        dst[(h * SEQ + mb + rg) * HD + d] = (bf16)acc[nt][rg];
    }
  }
}

// ---------------------------------------------------------------------------
// RMSNorm + rotary in place on Q and K ([h][t][d], d=64 = one wave).
// ATTN_SCALE folded into Q (post-norm; rotary is linear -> exact).
// ---------------------------------------------------------------------------
__global__ __launch_bounds__(256) void norm_rope(bf16* __restrict__ Qb, bf16* __restrict__ Kb)
{
  const int row = blockIdx.x * 4 + (threadIdx.x >> 6);
  const int lane = threadIdx.x & 63;
  const bool isQ = row < NH * SEQ;
  bf16* base = isQ ? Qb : Kb;
  const int hr = isQ ? row : row - NH * SEQ;   // h*SEQ + t
  const int t = hr & (SEQ - 1);
  bf16* p = base + (size_t)hr * HD;

  float x = (float)p[lane];
  float ss = x * x;
#pragma unroll
  for (int off = 32; off; off >>= 1) ss += __shfl_xor(ss, off, 64);
  float xn = x * rsqrtf(ss * (1.0f / 64.0f) + RMS_EPS);
  float xp = __shfl_xor(xn, 32, 64);           // rotary partner (d ^ 32)
  const int i = lane & 31;
  float fr = (i < 16) ? exp2f(-10.0f * (float)i * (1.0f / 15.0f)) : 0.0f;
  float th = (float)t * fr;
  float sn, cs;
  sincosf(th, &sn, &cs);
  float y = xn * cs + ((lane < 32) ? xp * sn : -xp * sn);
  if (isQ) y *= ATTN_SCALE;
  p[lane] = (bf16)y;
}

// ---------------------------------------------------------------------------
// Flash attention: block = (head, 64 q-rows), 4 waves x 16 rows.
// s-tiles of 64; online softmax; P: C-layout -> wave-private LDS -> A-layout.
// ---------------------------------------------------------------------------
__global__ __launch_bounds__(256) void flash_attn(
    const bf16* __restrict__ Qb, const bf16* __restrict__ Kb,
    const bf16* __restrict__ Vt, bf16* __restrict__ Y)
{
  __shared__ bf16 Ks[64][72];
  __shared__ bf16 Vts[64][72];
  __shared__ bf16 Ps[4][16][72];
  const int h = blockIdx.y;
  const int qb = blockIdx.x;
  const int qi = (qb & 1) ? (63 - (qb >> 1)) : (qb >> 1);  // light/heavy pairing
  const int q0 = qi * 64;
  const int tid = threadIdx.x;
  const int lane = tid & 63, w = tid >> 6;
  const int c16 = lane & 15, q4 = lane >> 4;
  const int sr = tid >> 3, sc = tid & 7;          // 32 rows x 64 cols; 2 passes

  const int tq = q0 + w * 16 + c16;
  bf16x8 aq0 = *(const bf16x8*)&Qb[((h * SEQ) + tq) * HD + q4 * 8];
  bf16x8 aq1 = *(const bf16x8*)&Qb[((h * SEQ) + tq) * HD + 32 + q4 * 8];

  const f32x4 vzero = {0.f, 0.f, 0.f, 0.f};
  f32x4 O[4] = {vzero, vzero, vzero, vzero};
  float m_i[4], l_i[4];
#pragma unroll
  for (int rg = 0; rg < 4; rg++) { m_i[rg] = NEG_INF; l_i[rg] = 0.f; }
  const int t_my0 = q0 + w * 16 + q4 * 4;

  for (int s0 = 0; s0 <= q0; s0 += 64) {
    __syncthreads();
#pragma unroll
    for (int half = 0; half < 2; half++) {
      const int r = sr + half * 32;
      *(bf16x8*)&Ks[r][sc * 8]  = *(const bf16x8*)&Kb[((h * SEQ) + s0 + r) * HD + sc * 8];
      *(bf16x8*)&Vts[r][sc * 8] = *(const bf16x8*)&Vt[((h * HD) + r) * SEQ + s0 + sc * 8];
    }
    __syncthreads();

    f32x4 S[4];
#pragma unroll
    for (int nt = 0; nt < 4; nt++) {
      bf16x8 b0 = *(const bf16x8*)&Ks[nt * 16 + c16][q4 * 8];
      bf16x8 b1 = *(const bf16x8*)&Ks[nt * 16 + c16][32 + q4 * 8];
      f32x4 z = vzero;
      z = MFMA_BF16(aq0, b0, z);
      z = MFMA_BF16(aq1, b1, z);
      S[nt] = z;
    }
#pragma unroll
    for (int nt = 0; nt < 4; nt++) {
      const int s_g = s0 + nt * 16 + c16;
#pragma unroll
      for (int rg = 0; rg < 4; rg++)
        if (s_g > t_my0 + rg) S[nt][rg] = NEG_INF;
    }
#pragma unroll
    for (int rg = 0; rg < 4; rg++) {
      float v = fmaxf(fmaxf(S[0][rg], S[1][rg]), fmaxf(S[2][rg], S[3][rg]));
      v = fmaxf(v, __shfl_xor(v, 1, 64));
      v = fmaxf(v, __shfl_xor(v, 2, 64));
      v = fmaxf(v, __shfl_xor(v, 4, 64));
      v = fmaxf(v, __shfl_xor(v, 8, 64));
      const float mnew = fmaxf(m_i[rg], v);
      const float alpha = __expf(m_i[rg] - mnew);
      float ps = 0.f;
#pragma unroll
      for (int nt = 0; nt < 4; nt++) {
        float pv = __expf(S[nt][rg] - mnew);
        S[nt][rg] = pv;
        ps += pv;
      }
      ps += __shfl_xor(ps, 1, 64);
      ps += __shfl_xor(ps, 2, 64);
      ps += __shfl_xor(ps, 4, 64);
      ps += __shfl_xor(ps, 8, 64);
      l_i[rg] = l_i[rg] * alpha + ps;
      m_i[rg] = mnew;
#pragma unroll
      for (int dt = 0; dt < 4; dt++) O[dt][rg] *= alpha;
    }
#pragma unroll
    for (int nt = 0; nt < 4; nt++)
#pragma unroll
      for (int rg = 0; rg < 4; rg++)
        Ps[w][q4 * 4 + rg][nt * 16 + c16] = (bf16)S[nt][rg];
    bf16x8 ap0 = *(const bf16x8*)&Ps[w][c16][q4 * 8];
    bf16x8 ap1 = *(const bf16x8*)&Ps[w][c16][32 + q4 * 8];
#pragma unroll
    for (int dt = 0; dt < 4; dt++) {
      bf16x8 bv0 = *(const bf16x8*)&Vts[dt * 16 + c16][q4 * 8];
      bf16x8 bv1 = *(const bf16x8*)&Vts[dt * 16 + c16][32 + q4 * 8];
      O[dt] = MFMA_BF16(ap0, bv0, O[dt]);
      O[dt] = MFMA_BF16(ap1, bv1, O[dt]);
    }
  }
#pragma unroll
  for (int dt = 0; dt < 4; dt++)
#pragma unroll
    for (int rg = 0; rg < 4; rg++) {
      const int t_g = t_my0 + rg;
      Y[(size_t)t_g * DM + h * HD + dt * 16 + c16] = (bf16)(O[dt][rg] / l_i[rg]);
    }
}

// ---------------------------------------------------------------------------
// out[m][n] = sum_k Y[m][k] * c_proj_w[n][k] -- FP32 store to d_out.
// ---------------------------------------------------------------------------
__global__ __launch_bounds__(256) void gemm_proj(
    const bf16* __restrict__ A,      // Y: [SEQ][DM]
    const bf16* __restrict__ B,      // c_proj_w bf16 copy: [DM][DM]
    float* __restrict__ C)
{
  __shared__ bf16 As[64][40];
  __shared__ bf16 Bs[64][40];
  const int m0 = blockIdx.x * 64, n0 = blockIdx.y * 64;
  const int tid = threadIdx.x;
  const int lane = tid & 63, w = tid >> 6;
  const int c16 = lane & 15, q4 = lane >> 4;
  const int sr = tid >> 2, sc = tid & 3;
  const f32x4 vzero = {0.f, 0.f, 0.f, 0.f};
  f32x4 acc[4] = {vzero, vzero, vzero, vzero};

  for (int k0 = 0; k0 < DM; k0 += 32) {
    *(bf16x8*)&As[sr][sc * 8] = *(const bf16x8*)&A[(m0 + sr) * DM + k0 + sc * 8];
    *(bf16x8*)&Bs[sr][sc * 8] = *(const bf16x8*)&B[(n0 + sr) * DM + k0 + sc * 8];
    __syncthreads();
    bf16x8 af = *(const bf16x8*)&As[w * 16 + c16][q4 * 8];
#pragma unroll
    for (int nt = 0; nt < 4; nt++) {
      bf16x8 bfr = *(const bf16x8*)&Bs[nt * 16 + c16][q4 * 8];
      acc[nt] = MFMA_BF16(af, bfr, acc[nt]);
    }
    __syncthreads();
  }
#pragma unroll
  for (int nt = 0; nt < 4; nt++) {
    const int n = n0 + nt * 16 + c16;
#pragma unroll
    for (int rg = 0; rg < 4; rg++) {
      const int m = m0 + w * 16 + q4 * 4 + rg;
      C[(size_t)m * DM + n] = acc[nt][rg];       // fp32 output
    }
  }
}

// ---------------------------------------------------------------------------
extern "C" void kernel_launch(void* const* d_in, const int* in_sizes, int n_in,
                              void* d_out, int out_size, void* d_ws, size_t ws_size,
                              hipStream_t stream)
{
  (void)in_sizes; (void)n_in; (void)out_size; (void)ws_size;
  const float* x      = (const float*)d_in[0];
  const float* qkvw   = (const float*)d_in[1];
  const float* cprojw = (const float*)d_in[2];
  float* outp = (float*)d_out;

  const int NX = SEQ * DM;         // 3,145,728
  const int NW = NQKV * DM;        // 1,769,472
  const int NP = DM * DM;          //   589,824

  char* ws = (char*)d_ws;
  bf16* xb    = (bf16*)(ws);                              // 6,291,456 B
  bf16* wqkv  = (bf16*)(ws + 6291456);                    // 3,538,944 B
  bf16* wproj = (bf16*)(ws + 9830400);                    // 1,179,648 B
  char* ws2   = ws + 11010048;
  const size_t SZ = (size_t)NH * SEQ * HD * sizeof(bf16); // 6,291,456 B
  bf16* Q  = (bf16*)(ws2);
  bf16* K  = (bf16*)(ws2 + SZ);
  bf16* Vt = (bf16*)(ws2 + 2 * SZ);
  bf16* Y  = (bf16*)(ws2 + 3 * SZ);                       // total ws ~34.5 MB

  convert_in<<<dim3(NX / 2048), 256, 0, stream>>>(x,      xb,    NX);
  convert_in<<<dim3(NW / 2048), 256, 0, stream>>>(qkvw,   wqkv,  NW);
  convert_in<<<dim3(NP / 2048), 256, 0, stream>>>(cprojw, wproj, NP);

  gemm_qkv  <<<dim3(SEQ / 64, NQKV / 64), 256, 0, stream>>>(xb, wqkv, Q, K, Vt);
  norm_rope <<<dim3(2 * NH * SEQ / 4),    256, 0, stream>>>(Q, K);
  flash_attn<<<dim3(SEQ / 64, NH),        256, 0, stream>>>(Q, K, Vt, Y);
  gemm_proj <<<dim3(SEQ / 64, DM / 64),   256, 0, stream>>>(Y, wproj, outp);
}

// Round 7
// 318.287 us; speedup vs baseline: 1.0200x; 1.0200x over previous
//
#include <hip/hip_runtime.h>
#include <math.h>

// Round 7: R6 design, compile fix only (no #pragma inside macro args — GEMM
// core is now a __device__ inline helper; per-kernel epilogues in plain code).
// flash split-K P=2 + 128x128 GEMM tiles. Semantics locked by R5.

typedef __bf16 bf16;
typedef __bf16 bf16x8 __attribute__((ext_vector_type(8)));
typedef float  f32x4  __attribute__((ext_vector_type(4)));

#define MFMA_BF16(a, b, c) __builtin_amdgcn_mfma_f32_16x16x32_bf16((a), (b), (c), 0, 0, 0)

#define SEQ  4096
#define NH   12
#define HD   64
#define DM   768
#define NQKV 2304
#define NPART 2
#define ATTN_SCALE 0.12f
#define RMS_EPS 1.1920928955078125e-07f
#define NEG_INF -3.0e38f

// ---------------------------------------------------------------------------
__global__ __launch_bounds__(256) void convert_in(const float* __restrict__ src,
                                                  bf16* __restrict__ dst, int n)
{
  const int i0 = (blockIdx.x * 256 + threadIdx.x) * 8;
  if (i0 >= n) return;
  f32x4 a = *(const f32x4*)(src + i0);
  f32x4 b = *(const f32x4*)(src + i0 + 4);
  bf16x8 o;
#pragma unroll
  for (int j = 0; j < 4; j++) { o[j] = (bf16)a[j]; o[j + 4] = (bf16)b[j]; }
  *(bf16x8*)(dst + i0) = o;
}

// ---------------------------------------------------------------------------
// 128x128-tile GEMM core (BK=32, 4 waves in 2x2 quadrants of 64x64; 16 MFMA +
// 8 ds_read_b128 per k-step). Computes acc[mq][nq] for this thread's wave.
// C[m][n] = sum_k A[m][k]*B[n][k]; caller does the epilogue.
// ---------------------------------------------------------------------------
__device__ __forceinline__ void gemm128_core(
    const bf16* __restrict__ A, const bf16* __restrict__ B,
    int m0, int n0, bf16 (*As)[40], bf16 (*Bs)[40], f32x4 acc[4][4])
{
  const int tid = threadIdx.x;
  const int lane = tid & 63, w = tid >> 6;
  const int c16 = lane & 15, q4 = lane >> 4;
  const int mo = (w & 1) * 64, no = (w >> 1) * 64;
  const int srow = tid >> 2, scol = (tid & 3) * 8;
  const f32x4 vzero = {0.f, 0.f, 0.f, 0.f};
#pragma unroll
  for (int i = 0; i < 4; i++)
#pragma unroll
    for (int j = 0; j < 4; j++) acc[i][j] = vzero;

  for (int k0 = 0; k0 < DM; k0 += 32) {
#pragma unroll
    for (int ps = 0; ps < 2; ps++) {
      const int r = srow + ps * 64;
      *(bf16x8*)&As[r][scol] = *(const bf16x8*)&A[(m0 + r) * DM + k0 + scol];
      *(bf16x8*)&Bs[r][scol] = *(const bf16x8*)&B[(n0 + r) * DM + k0 + scol];
    }
    __syncthreads();
    bf16x8 ar[4], br[4];
#pragma unroll
    for (int mq = 0; mq < 4; mq++)
      ar[mq] = *(const bf16x8*)&As[mo + mq * 16 + c16][q4 * 8];
#pragma unroll
    for (int nq = 0; nq < 4; nq++)
      br[nq] = *(const bf16x8*)&Bs[no + nq * 16 + c16][q4 * 8];
#pragma unroll
    for (int mq = 0; mq < 4; mq++)
#pragma unroll
      for (int nq = 0; nq < 4; nq++)
        acc[mq][nq] = MFMA_BF16(ar[mq], br[nq], acc[mq][nq]);
    __syncthreads();
  }
}

// QKV GEMM: N=2304 = 18 blocks of 128; blockIdx.y 0-5 -> Q, 6-11 -> K, 12-17 -> V^T.
__global__ __launch_bounds__(256) void gemm_qkv(
    const bf16* __restrict__ A, const bf16* __restrict__ B,
    bf16* __restrict__ Qb, bf16* __restrict__ Kb, bf16* __restrict__ Vt)
{
  __shared__ bf16 As[128][40];
  __shared__ bf16 Bs[128][40];
  const int m0 = blockIdx.x * 128, n0 = blockIdx.y * 128;
  f32x4 acc[4][4];
  gemm128_core(A, B, m0, n0, As, Bs, acc);

  const int lane = threadIdx.x & 63, w = threadIdx.x >> 6;
  const int c16 = lane & 15, q4 = lane >> 4;
  const int mo = (w & 1) * 64, no = (w >> 1) * 64;
  const int kidx = blockIdx.y / 6;
  const int rbase = n0 - kidx * DM;
#pragma unroll
  for (int nq = 0; nq < 4; nq++) {
    const int rr = rbase + no + nq * 16 + c16;
    const int h = rr >> 6, d = rr & 63;
#pragma unroll
    for (int mq = 0; mq < 4; mq++) {
      const int mb = m0 + mo + mq * 16 + q4 * 4;
      if (kidx == 2) {
#pragma unroll
        for (int rg = 0; rg < 4; rg++)
          Vt[((h * HD) + d) * SEQ + mb + rg] = (bf16)acc[mq][nq][rg];
      } else {
        bf16* dst = kidx ? Kb : Qb;
#pragma unroll
        for (int rg = 0; rg < 4; rg++)
          dst[(h * SEQ + mb + rg) * HD + d] = (bf16)acc[mq][nq][rg];
      }
    }
  }
}

// Projection GEMM: fp32 store to d_out.
__global__ __launch_bounds__(256) void gemm_proj(
    const bf16* __restrict__ A, const bf16* __restrict__ B, float* __restrict__ C)
{
  __shared__ bf16 As[128][40];
  __shared__ bf16 Bs[128][40];
  const int m0 = blockIdx.x * 128, n0 = blockIdx.y * 128;
  f32x4 acc[4][4];
  gemm128_core(A, B, m0, n0, As, Bs, acc);

  const int lane = threadIdx.x & 63, w = threadIdx.x >> 6;
  const int c16 = lane & 15, q4 = lane >> 4;
  const int mo = (w & 1) * 64, no = (w >> 1) * 64;
#pragma unroll
  for (int nq = 0; nq < 4; nq++) {
    const int n = n0 + no + nq * 16 + c16;
#pragma unroll
    for (int mq = 0; mq < 4; mq++) {
      const int mb = m0 + mo + mq * 16 + q4 * 4;
#pragma unroll
      for (int rg = 0; rg < 4; rg++)
        C[(size_t)(mb + rg) * DM + n] = acc[mq][nq][rg];
    }
  }
}

// ---------------------------------------------------------------------------
// RMSNorm + rotary in place on Q and K; ATTN_SCALE folded into Q.
// ---------------------------------------------------------------------------
__global__ __launch_bounds__(256) void norm_rope(bf16* __restrict__ Qb, bf16* __restrict__ Kb)
{
  const int row = blockIdx.x * 4 + (threadIdx.x >> 6);
  const int lane = threadIdx.x & 63;
  const bool isQ = row < NH * SEQ;
  bf16* base = isQ ? Qb : Kb;
  const int hr = isQ ? row : row - NH * SEQ;
  const int t = hr & (SEQ - 1);
  bf16* p = base + (size_t)hr * HD;

  float x = (float)p[lane];
  float ss = x * x;
#pragma unroll
  for (int off = 32; off; off >>= 1) ss += __shfl_xor(ss, off, 64);
  float xn = x * rsqrtf(ss * (1.0f / 64.0f) + RMS_EPS);
  float xp = __shfl_xor(xn, 32, 64);
  const int i = lane & 31;
  float fr = (i < 16) ? exp2f(-10.0f * (float)i * (1.0f / 15.0f)) : 0.0f;
  float th = (float)t * fr;
  float sn, cs;
  sincosf(th, &sn, &cs);
  float y = xn * cs + ((lane < 32) ? xp * sn : -xp * sn);
  if (isQ) y *= ATTN_SCALE;
  p[lane] = (bf16)y;
}

// ---------------------------------------------------------------------------
// Flash attention partial: block = (q-block qi, head h, partition p).
// Partition p handles s-tiles j = p, p+NPART, ...; writes fp32 O, m, l.
// ---------------------------------------------------------------------------
__global__ __launch_bounds__(256) void flash_partial(
    const bf16* __restrict__ Qb, const bf16* __restrict__ Kb,
    const bf16* __restrict__ Vt, float* __restrict__ Opart,
    float* __restrict__ Mpart, float* __restrict__ Lpart)
{
  __shared__ bf16 Ks[64][72];
  __shared__ bf16 Vts[64][72];
  __shared__ bf16 Ps[4][16][72];
  const int h = blockIdx.y, p = blockIdx.z;
  const int qb = blockIdx.x;
  const int qi = (qb & 1) ? (63 - (qb >> 1)) : (qb >> 1);  // light/heavy pairing
  const int q0 = qi * 64;
  const int tid = threadIdx.x;
  const int lane = tid & 63, w = tid >> 6;
  const int c16 = lane & 15, q4 = lane >> 4;
  const int sr = tid >> 3, sc = tid & 7;

  const int tq = q0 + w * 16 + c16;
  bf16x8 aq0 = *(const bf16x8*)&Qb[((h * SEQ) + tq) * HD + q4 * 8];
  bf16x8 aq1 = *(const bf16x8*)&Qb[((h * SEQ) + tq) * HD + 32 + q4 * 8];

  const f32x4 vzero = {0.f, 0.f, 0.f, 0.f};
  f32x4 O[4] = {vzero, vzero, vzero, vzero};
  float m_i[4], l_i[4];
#pragma unroll
  for (int rg = 0; rg < 4; rg++) { m_i[rg] = NEG_INF; l_i[rg] = 0.f; }
  const int t_my0 = q0 + w * 16 + q4 * 4;

  for (int s0 = p * 64; s0 <= q0; s0 += NPART * 64) {
    __syncthreads();
#pragma unroll
    for (int half = 0; half < 2; half++) {
      const int r = sr + half * 32;
      *(bf16x8*)&Ks[r][sc * 8]  = *(const bf16x8*)&Kb[((h * SEQ) + s0 + r) * HD + sc * 8];
      *(bf16x8*)&Vts[r][sc * 8] = *(const bf16x8*)&Vt[((h * HD) + r) * SEQ + s0 + sc * 8];
    }
    __syncthreads();

    f32x4 S[4];
#pragma unroll
    for (int nt = 0; nt < 4; nt++) {
      bf16x8 b0 = *(const bf16x8*)&Ks[nt * 16 + c16][q4 * 8];
      bf16x8 b1 = *(const bf16x8*)&Ks[nt * 16 + c16][32 + q4 * 8];
      f32x4 z = vzero;
      z = MFMA_BF16(aq0, b0, z);
      z = MFMA_BF16(aq1, b1, z);
      S[nt] = z;
    }
#pragma unroll
    for (int nt = 0; nt < 4; nt++) {
      const int s_g = s0 + nt * 16 + c16;
#pragma unroll
      for (int rg = 0; rg < 4; rg++)
        if (s_g > t_my0 + rg) S[nt][rg] = NEG_INF;
    }
#pragma unroll
    for (int rg = 0; rg < 4; rg++) {
      float v = fmaxf(fmaxf(S[0][rg], S[1][rg]), fmaxf(S[2][rg], S[3][rg]));
      v = fmaxf(v, __shfl_xor(v, 1, 64));
      v = fmaxf(v, __shfl_xor(v, 2, 64));
      v = fmaxf(v, __shfl_xor(v, 4, 64));
      v = fmaxf(v, __shfl_xor(v, 8, 64));
      const float mnew = fmaxf(m_i[rg], v);
      const float alpha = __expf(m_i[rg] - mnew);
      float ps = 0.f;
#pragma unroll
      for (int nt = 0; nt < 4; nt++) {
        float pv = __expf(S[nt][rg] - mnew);
        S[nt][rg] = pv;
        ps += pv;
      }
      ps += __shfl_xor(ps, 1, 64);
      ps += __shfl_xor(ps, 2, 64);
      ps += __shfl_xor(ps, 4, 64);
      ps += __shfl_xor(ps, 8, 64);
      l_i[rg] = l_i[rg] * alpha + ps;
      m_i[rg] = mnew;
#pragma unroll
      for (int dt = 0; dt < 4; dt++) O[dt][rg] *= alpha;
    }
#pragma unroll
    for (int nt = 0; nt < 4; nt++)
#pragma unroll
      for (int rg = 0; rg < 4; rg++)
        Ps[w][q4 * 4 + rg][nt * 16 + c16] = (bf16)S[nt][rg];
    bf16x8 ap0 = *(const bf16x8*)&Ps[w][c16][q4 * 8];
    bf16x8 ap1 = *(const bf16x8*)&Ps[w][c16][32 + q4 * 8];
#pragma unroll
    for (int dt = 0; dt < 4; dt++) {
      bf16x8 bv0 = *(const bf16x8*)&Vts[dt * 16 + c16][q4 * 8];
      bf16x8 bv1 = *(const bf16x8*)&Vts[dt * 16 + c16][32 + q4 * 8];
      O[dt] = MFMA_BF16(ap0, bv0, O[dt]);
      O[dt] = MFMA_BF16(ap1, bv1, O[dt]);
    }
  }
  // write partials (no normalization here)
  const int u = ((h * 64 + qi) * NPART + p);
  float* Op = Opart + (size_t)u * 4096;
#pragma unroll
  for (int dt = 0; dt < 4; dt++)
#pragma unroll
    for (int rg = 0; rg < 4; rg++)
      Op[(w * 16 + q4 * 4 + rg) * 64 + dt * 16 + c16] = O[dt][rg];
  if (c16 == 0) {
#pragma unroll
    for (int rg = 0; rg < 4; rg++) {
      Mpart[u * 64 + w * 16 + q4 * 4 + rg] = m_i[rg];
      Lpart[u * 64 + w * 16 + q4 * 4 + rg] = l_i[rg];
    }
  }
}

// ---------------------------------------------------------------------------
// Combine NPART partials -> Y bf16 [t][h*64+d]. Block per (qi, h).
// ---------------------------------------------------------------------------
__global__ __launch_bounds__(256) void flash_combine(
    const float* __restrict__ Opart, const float* __restrict__ Mpart,
    const float* __restrict__ Lpart, bf16* __restrict__ Y)
{
  const int qi = blockIdx.x, h = blockIdx.y;
  const int row = threadIdx.x >> 2, cg = (threadIdx.x & 3) * 16;
  const int u0 = (h * 64 + qi) * NPART;
  const float m0 = Mpart[u0 * 64 + row], m1 = Mpart[(u0 + 1) * 64 + row];
  const float mg = fmaxf(m0, m1);
  const float s0 = __expf(m0 - mg), s1 = __expf(m1 - mg);
  const float inv = 1.0f / (Lpart[u0 * 64 + row] * s0 + Lpart[(u0 + 1) * 64 + row] * s1);
  const float* O0 = Opart + (size_t)u0 * 4096 + row * 64 + cg;
  const float* O1 = O0 + 4096;
  bf16* yp = Y + (size_t)(qi * 64 + row) * DM + h * HD + cg;
#pragma unroll
  for (int j = 0; j < 16; j += 4) {
    f32x4 a = *(const f32x4*)(O0 + j);
    f32x4 b = *(const f32x4*)(O1 + j);
#pragma unroll
    for (int e = 0; e < 4; e++) yp[j + e] = (bf16)((a[e] * s0 + b[e] * s1) * inv);
  }
}

// ---------------------------------------------------------------------------
extern "C" void kernel_launch(void* const* d_in, const int* in_sizes, int n_in,
                              void* d_out, int out_size, void* d_ws, size_t ws_size,
                              hipStream_t stream)
{
  (void)in_sizes; (void)n_in; (void)out_size; (void)ws_size;
  const float* x      = (const float*)d_in[0];
  const float* qkvw   = (const float*)d_in[1];
  const float* cprojw = (const float*)d_in[2];
  float* outp = (float*)d_out;

  const int NX = SEQ * DM, NW = NQKV * DM, NP = DM * DM;

  char* ws = (char*)d_ws;
  bf16*  xb    = (bf16*)(ws);                       // 6,291,456
  bf16*  wqkv  = (bf16*)(ws + 6291456);             // 3,538,944
  bf16*  wproj = (bf16*)(ws + 9830400);             // 1,179,648
  bf16*  Q     = (bf16*)(ws + 11010048);            // 6,291,456
  bf16*  K     = (bf16*)(ws + 17301504);            // 6,291,456
  bf16*  Vt    = (bf16*)(ws + 23592960);            // 6,291,456
  bf16*  Y     = (bf16*)(ws + 29884416);            // 6,291,456
  float* Opart = (float*)(ws + 36175872);           // 25,165,824
  float* Mpart = (float*)(ws + 61341696);           //    393,216
  float* Lpart = (float*)(ws + 61734912);           //    393,216  (total 62.1 MB)

  convert_in<<<dim3(NX / 2048), 256, 0, stream>>>(x,      xb,    NX);
  convert_in<<<dim3(NW / 2048), 256, 0, stream>>>(qkvw,   wqkv,  NW);
  convert_in<<<dim3(NP / 2048), 256, 0, stream>>>(cprojw, wproj, NP);

  gemm_qkv     <<<dim3(SEQ / 128, NQKV / 128), 256, 0, stream>>>(xb, wqkv, Q, K, Vt);
  norm_rope    <<<dim3(2 * NH * SEQ / 4),      256, 0, stream>>>(Q, K);
  flash_partial<<<dim3(SEQ / 64, NH, NPART),   256, 0, stream>>>(Q, K, Vt, Opart, Mpart, Lpart);
  flash_combine<<<dim3(SEQ / 64, NH),          256, 0, stream>>>(Opart, Mpart, Lpart, Y);
  gemm_proj    <<<dim3(SEQ / 128, DM / 128),   256, 0, stream>>>(Y, wproj, outp);
}

// Round 8
// 253.734 us; speedup vs baseline: 1.2795x; 1.2544x over previous
//
#include <hip/hip_runtime.h>
#include <math.h>

// Round 8: flash rewrite — NO online softmax. Cauchy-Schwarz bounds scores to
// |s| <= 0.12*8*8 = 7.68 (RMS-normed q,k), so exp(s) needs no max-shift:
// inner loop has ZERO cross-lane ops (l reduced once at end). K/V register
// prefetch overlaps global latency. GEMMs unchanged from R7.

typedef __bf16 bf16;
typedef __bf16 bf16x8 __attribute__((ext_vector_type(8)));
typedef float  f32x4  __attribute__((ext_vector_type(4)));

#define MFMA_BF16(a, b, c) __builtin_amdgcn_mfma_f32_16x16x32_bf16((a), (b), (c), 0, 0, 0)

#define SEQ  4096
#define NH   12
#define HD   64
#define DM   768
#define NQKV 2304
#define NPART 2
#define ATTN_SCALE 0.12f
#define RMS_EPS 1.1920928955078125e-07f

// ---------------------------------------------------------------------------
__global__ __launch_bounds__(256) void convert_in(const float* __restrict__ src,
                                                  bf16* __restrict__ dst, int n)
{
  const int i0 = (blockIdx.x * 256 + threadIdx.x) * 8;
  if (i0 >= n) return;
  f32x4 a = *(const f32x4*)(src + i0);
  f32x4 b = *(const f32x4*)(src + i0 + 4);
  bf16x8 o;
#pragma unroll
  for (int j = 0; j < 4; j++) { o[j] = (bf16)a[j]; o[j + 4] = (bf16)b[j]; }
  *(bf16x8*)(dst + i0) = o;
}

// ---------------------------------------------------------------------------
// 128x128-tile GEMM core (BK=32, 4 waves in 2x2 quadrants of 64x64).
// ---------------------------------------------------------------------------
__device__ __forceinline__ void gemm128_core(
    const bf16* __restrict__ A, const bf16* __restrict__ B,
    int m0, int n0, bf16 (*As)[40], bf16 (*Bs)[40], f32x4 acc[4][4])
{
  const int tid = threadIdx.x;
  const int lane = tid & 63, w = tid >> 6;
  const int c16 = lane & 15, q4 = lane >> 4;
  const int mo = (w & 1) * 64, no = (w >> 1) * 64;
  const int srow = tid >> 2, scol = (tid & 3) * 8;
  const f32x4 vzero = {0.f, 0.f, 0.f, 0.f};
#pragma unroll
  for (int i = 0; i < 4; i++)
#pragma unroll
    for (int j = 0; j < 4; j++) acc[i][j] = vzero;

  for (int k0 = 0; k0 < DM; k0 += 32) {
#pragma unroll
    for (int ps = 0; ps < 2; ps++) {
      const int r = srow + ps * 64;
      *(bf16x8*)&As[r][scol] = *(const bf16x8*)&A[(m0 + r) * DM + k0 + scol];
      *(bf16x8*)&Bs[r][scol] = *(const bf16x8*)&B[(n0 + r) * DM + k0 + scol];
    }
    __syncthreads();
    bf16x8 ar[4], br[4];
#pragma unroll
    for (int mq = 0; mq < 4; mq++)
      ar[mq] = *(const bf16x8*)&As[mo + mq * 16 + c16][q4 * 8];
#pragma unroll
    for (int nq = 0; nq < 4; nq++)
      br[nq] = *(const bf16x8*)&Bs[no + nq * 16 + c16][q4 * 8];
#pragma unroll
    for (int mq = 0; mq < 4; mq++)
#pragma unroll
      for (int nq = 0; nq < 4; nq++)
        acc[mq][nq] = MFMA_BF16(ar[mq], br[nq], acc[mq][nq]);
    __syncthreads();
  }
}

__global__ __launch_bounds__(256) void gemm_qkv(
    const bf16* __restrict__ A, const bf16* __restrict__ B,
    bf16* __restrict__ Qb, bf16* __restrict__ Kb, bf16* __restrict__ Vt)
{
  __shared__ bf16 As[128][40];
  __shared__ bf16 Bs[128][40];
  const int m0 = blockIdx.x * 128, n0 = blockIdx.y * 128;
  f32x4 acc[4][4];
  gemm128_core(A, B, m0, n0, As, Bs, acc);

  const int lane = threadIdx.x & 63, w = threadIdx.x >> 6;
  const int c16 = lane & 15, q4 = lane >> 4;
  const int mo = (w & 1) * 64, no = (w >> 1) * 64;
  const int kidx = blockIdx.y / 6;
  const int rbase = n0 - kidx * DM;
#pragma unroll
  for (int nq = 0; nq < 4; nq++) {
    const int rr = rbase + no + nq * 16 + c16;
    const int h = rr >> 6, d = rr & 63;
#pragma unroll
    for (int mq = 0; mq < 4; mq++) {
      const int mb = m0 + mo + mq * 16 + q4 * 4;
      if (kidx == 2) {
#pragma unroll
        for (int rg = 0; rg < 4; rg++)
          Vt[((h * HD) + d) * SEQ + mb + rg] = (bf16)acc[mq][nq][rg];
      } else {
        bf16* dst = kidx ? Kb : Qb;
#pragma unroll
        for (int rg = 0; rg < 4; rg++)
          dst[(h * SEQ + mb + rg) * HD + d] = (bf16)acc[mq][nq][rg];
      }
    }
  }
}

__global__ __launch_bounds__(256) void gemm_proj(
    const bf16* __restrict__ A, const bf16* __restrict__ B, float* __restrict__ C)
{
  __shared__ bf16 As[128][40];
  __shared__ bf16 Bs[128][40];
  const int m0 = blockIdx.x * 128, n0 = blockIdx.y * 128;
  f32x4 acc[4][4];
  gemm128_core(A, B, m0, n0, As, Bs, acc);

  const int lane = threadIdx.x & 63, w = threadIdx.x >> 6;
  const int c16 = lane & 15, q4 = lane >> 4;
  const int mo = (w & 1) * 64, no = (w >> 1) * 64;
#pragma unroll
  for (int nq = 0; nq < 4; nq++) {
    const int n = n0 + no + nq * 16 + c16;
#pragma unroll
    for (int mq = 0; mq < 4; mq++) {
      const int mb = m0 + mo + mq * 16 + q4 * 4;
#pragma unroll
      for (int rg = 0; rg < 4; rg++)
        C[(size_t)(mb + rg) * DM + n] = acc[mq][nq][rg];
    }
  }
}

// ---------------------------------------------------------------------------
__global__ __launch_bounds__(256) void norm_rope(bf16* __restrict__ Qb, bf16* __restrict__ Kb)
{
  const int row = blockIdx.x * 4 + (threadIdx.x >> 6);
  const int lane = threadIdx.x & 63;
  const bool isQ = row < NH * SEQ;
  bf16* base = isQ ? Qb : Kb;
  const int hr = isQ ? row : row - NH * SEQ;
  const int t = hr & (SEQ - 1);
  bf16* p = base + (size_t)hr * HD;

  float x = (float)p[lane];
  float ss = x * x;
#pragma unroll
  for (int off = 32; off; off >>= 1) ss += __shfl_xor(ss, off, 64);
  float xn = x * rsqrtf(ss * (1.0f / 64.0f) + RMS_EPS);
  float xp = __shfl_xor(xn, 32, 64);
  const int i = lane & 31;
  float fr = (i < 16) ? exp2f(-10.0f * (float)i * (1.0f / 15.0f)) : 0.0f;
  float th = (float)t * fr;
  float sn, cs;
  sincosf(th, &sn, &cs);
  float y = xn * cs + ((lane < 32) ? xp * sn : -xp * sn);
  if (isQ) y *= ATTN_SCALE;
  p[lane] = (bf16)y;
}

// ---------------------------------------------------------------------------
// Flash partial, fixed-scale softmax (scores bounded |s|<=7.68):
//   p = exp(s) directly; lane-local l accumulation; NO cross-lane ops in loop.
// K/V register prefetch overlaps global latency with compute.
// ---------------------------------------------------------------------------
__global__ __launch_bounds__(256) void flash_partial(
    const bf16* __restrict__ Qb, const bf16* __restrict__ Kb,
    const bf16* __restrict__ Vt, float* __restrict__ Opart,
    float* __restrict__ Lpart)
{
  __shared__ bf16 Ks[64][72];
  __shared__ bf16 Vts[64][72];
  __shared__ bf16 Ps[4][16][72];
  const int h = blockIdx.y, p = blockIdx.z;
  const int qb = blockIdx.x;
  const int qi = (qb & 1) ? (63 - (qb >> 1)) : (qb >> 1);  // light/heavy pairing
  const int q0 = qi * 64;
  const int tid = threadIdx.x;
  const int lane = tid & 63, w = tid >> 6;
  const int c16 = lane & 15, q4 = lane >> 4;
  const int sr = tid >> 3, sc8 = (tid & 7) * 8;    // 32 rows x 64 cols; 2 halves

  const int tq = q0 + w * 16 + c16;
  bf16x8 aq0 = *(const bf16x8*)&Qb[((h * SEQ) + tq) * HD + q4 * 8];
  bf16x8 aq1 = *(const bf16x8*)&Qb[((h * SEQ) + tq) * HD + 32 + q4 * 8];

  const f32x4 vzero = {0.f, 0.f, 0.f, 0.f};
  f32x4 O[4] = {vzero, vzero, vzero, vzero};
  float l_lane[4] = {0.f, 0.f, 0.f, 0.f};
  const int t_my0 = q0 + w * 16 + q4 * 4;

  const bf16* Kbase = Kb + (size_t)h * SEQ * HD;
  const bf16* Vbase = Vt + (size_t)h * HD * SEQ;

  const int sBeg = p * 64;
  if (sBeg <= q0) {
    // preload first tile into registers
    bf16x8 kr0 = *(const bf16x8*)&Kbase[(sBeg + sr) * HD + sc8];
    bf16x8 kr1 = *(const bf16x8*)&Kbase[(sBeg + sr + 32) * HD + sc8];
    bf16x8 vr0 = *(const bf16x8*)&Vbase[sr * SEQ + sBeg + sc8];
    bf16x8 vr1 = *(const bf16x8*)&Vbase[(sr + 32) * SEQ + sBeg + sc8];

    for (int s0 = sBeg; s0 <= q0; s0 += NPART * 64) {
      __syncthreads();                       // prior iteration's LDS reads done
      *(bf16x8*)&Ks[sr][sc8]       = kr0;
      *(bf16x8*)&Ks[sr + 32][sc8]  = kr1;
      *(bf16x8*)&Vts[sr][sc8]      = vr0;
      *(bf16x8*)&Vts[sr + 32][sc8] = vr1;
      __syncthreads();

      const int snext = s0 + NPART * 64;
      if (snext <= q0) {                     // prefetch next tile (no wait)
        kr0 = *(const bf16x8*)&Kbase[(snext + sr) * HD + sc8];
        kr1 = *(const bf16x8*)&Kbase[(snext + sr + 32) * HD + sc8];
        vr0 = *(const bf16x8*)&Vbase[sr * SEQ + snext + sc8];
        vr1 = *(const bf16x8*)&Vbase[(sr + 32) * SEQ + snext + sc8];
      }

      // S = Q K^T
      f32x4 S[4];
#pragma unroll
      for (int nt = 0; nt < 4; nt++) {
        bf16x8 b0 = *(const bf16x8*)&Ks[nt * 16 + c16][q4 * 8];
        bf16x8 b1 = *(const bf16x8*)&Ks[nt * 16 + c16][32 + q4 * 8];
        f32x4 z = vzero;
        z = MFMA_BF16(aq0, b0, z);
        z = MFMA_BF16(aq1, b1, z);
        S[nt] = z;
      }
      // mask + exp (no max shift: |s| <= 7.68 guaranteed) + lane-local l
#pragma unroll
      for (int nt = 0; nt < 4; nt++) {
        const int s_g = s0 + nt * 16 + c16;
#pragma unroll
        for (int rg = 0; rg < 4; rg++) {
          const float pv = (s_g > t_my0 + rg) ? 0.f : __expf(S[nt][rg]);
          S[nt][rg] = pv;
          l_lane[rg] += pv;
        }
      }
      // P: C-layout -> wave-private LDS -> A-layout
#pragma unroll
      for (int nt = 0; nt < 4; nt++)
#pragma unroll
        for (int rg = 0; rg < 4; rg++)
          Ps[w][q4 * 4 + rg][nt * 16 + c16] = (bf16)S[nt][rg];
      bf16x8 ap0 = *(const bf16x8*)&Ps[w][c16][q4 * 8];
      bf16x8 ap1 = *(const bf16x8*)&Ps[w][c16][32 + q4 * 8];
#pragma unroll
      for (int dt = 0; dt < 4; dt++) {
        bf16x8 bv0 = *(const bf16x8*)&Vts[dt * 16 + c16][q4 * 8];
        bf16x8 bv1 = *(const bf16x8*)&Vts[dt * 16 + c16][32 + q4 * 8];
        O[dt] = MFMA_BF16(ap0, bv0, O[dt]);
        O[dt] = MFMA_BF16(ap1, bv1, O[dt]);
      }
    }
  }
  // single end-of-kernel l reduction across the 16-lane row group
#pragma unroll
  for (int rg = 0; rg < 4; rg++) {
    float l = l_lane[rg];
    l += __shfl_xor(l, 1, 64);
    l += __shfl_xor(l, 2, 64);
    l += __shfl_xor(l, 4, 64);
    l += __shfl_xor(l, 8, 64);
    l_lane[rg] = l;
  }
  const int u = ((h * 64 + qi) * NPART + p);
  float* Op = Opart + (size_t)u * 4096;
#pragma unroll
  for (int dt = 0; dt < 4; dt++)
#pragma unroll
    for (int rg = 0; rg < 4; rg++)
      Op[(w * 16 + q4 * 4 + rg) * 64 + dt * 16 + c16] = O[dt][rg];
  if (c16 == 0) {
#pragma unroll
    for (int rg = 0; rg < 4; rg++)
      Lpart[u * 64 + w * 16 + q4 * 4 + rg] = l_lane[rg];
  }
}

// ---------------------------------------------------------------------------
// Combine: Y = (O0 + O1) / (l0 + l1). Block per (qi, h).
// ---------------------------------------------------------------------------
__global__ __launch_bounds__(256) void flash_combine(
    const float* __restrict__ Opart, const float* __restrict__ Lpart,
    bf16* __restrict__ Y)
{
  const int qi = blockIdx.x, h = blockIdx.y;
  const int row = threadIdx.x >> 2, cg = (threadIdx.x & 3) * 16;
  const int u0 = (h * 64 + qi) * NPART;
  const float inv = 1.0f / (Lpart[u0 * 64 + row] + Lpart[(u0 + 1) * 64 + row]);
  const float* O0 = Opart + (size_t)u0 * 4096 + row * 64 + cg;
  const float* O1 = O0 + 4096;
  bf16* yp = Y + (size_t)(qi * 64 + row) * DM + h * HD + cg;
#pragma unroll
  for (int j = 0; j < 16; j += 4) {
    f32x4 a = *(const f32x4*)(O0 + j);
    f32x4 b = *(const f32x4*)(O1 + j);
#pragma unroll
    for (int e = 0; e < 4; e++) yp[j + e] = (bf16)((a[e] + b[e]) * inv);
  }
}

// ---------------------------------------------------------------------------
extern "C" void kernel_launch(void* const* d_in, const int* in_sizes, int n_in,
                              void* d_out, int out_size, void* d_ws, size_t ws_size,
                              hipStream_t stream)
{
  (void)in_sizes; (void)n_in; (void)out_size; (void)ws_size;
  const float* x      = (const float*)d_in[0];
  const float* qkvw   = (const float*)d_in[1];
  const float* cprojw = (const float*)d_in[2];
  float* outp = (float*)d_out;

  const int NX = SEQ * DM, NW = NQKV * DM, NP = DM * DM;

  char* ws = (char*)d_ws;
  bf16*  xb    = (bf16*)(ws);                       // 6,291,456
  bf16*  wqkv  = (bf16*)(ws + 6291456);             // 3,538,944
  bf16*  wproj = (bf16*)(ws + 9830400);             // 1,179,648
  bf16*  Q     = (bf16*)(ws + 11010048);            // 6,291,456
  bf16*  K     = (bf16*)(ws + 17301504);            // 6,291,456
  bf16*  Vt    = (bf16*)(ws + 23592960);            // 6,291,456
  bf16*  Y     = (bf16*)(ws + 29884416);            // 6,291,456
  float* Opart = (float*)(ws + 36175872);           // 25,165,824
  float* Lpart = (float*)(ws + 61341696);           //    393,216  (total 61.7 MB)

  convert_in<<<dim3(NX / 2048), 256, 0, stream>>>(x,      xb,    NX);
  convert_in<<<dim3(NW / 2048), 256, 0, stream>>>(qkvw,   wqkv,  NW);
  convert_in<<<dim3(NP / 2048), 256, 0, stream>>>(cprojw, wproj, NP);

  gemm_qkv     <<<dim3(SEQ / 128, NQKV / 128), 256, 0, stream>>>(xb, wqkv, Q, K, Vt);
  norm_rope    <<<dim3(2 * NH * SEQ / 4),      256, 0, stream>>>(Q, K);
  flash_partial<<<dim3(SEQ / 64, NH, NPART),   256, 0, stream>>>(Q, K, Vt, Opart, Lpart);
  flash_combine<<<dim3(SEQ / 64, NH),          256, 0, stream>>>(Opart, Lpart, Y);
  gemm_proj    <<<dim3(SEQ / 128, DM / 128),   256, 0, stream>>>(Y, wproj, outp);
}